// Round 8
// baseline (184.107 us; speedup 1.0000x reference)
//
#include <hip/hip_runtime.h>

// Problem constants (fixed by the reference setup)
constexpr int N_IN  = 50000;
constexpr int C     = 64;
constexpr int T     = 8;
constexpr int E     = 800000;
constexpr int N_OUT = 50000;
constexpr int F     = 64;

// Two-level counting-sort parameters
constexpr int CHUNK   = 4096;                        // edges per chunk
constexpr int NCHUNK  = (E + CHUNK - 1) / CHUNK;     // 196
constexpr int NBIN_S  = (N_OUT + 255) / 256;         // 196 bins of 256 nodes
constexpr int LEN_CNT = NBIN_S * NCHUNK;             // 38416 counts entries
constexpr int SCA     = (LEN_CNT + 255) / 256;       // 151 scan chunks

// ---------------------------------------------------------------------------
// Workspace layout (bytes); total ~38.8 MB
// ---------------------------------------------------------------------------
constexpr size_t OFF_NFBF  = 0;                      // bf16 [N_IN][64]     6.4 MB
constexpr size_t OFF_KT    = 6400000;                // bf16 [64][512]      64 KB
constexpr size_t OFF_CNT   = OFF_KT + 65536;         // int [LEN_CNT] counts->offs
constexpr size_t OFF_BSUM  = OFF_CNT + 153664;       // int [SCA]
constexpr size_t OFF_START = OFF_BSUM + 1024;        // int [N_OUT+1]
constexpr size_t OFF_EFH   = OFF_START + 200064;     // f16 [E][8]         12.8 MB
constexpr size_t OFF_ENT   = OFF_EFH + 12800000;     // u32 [E] loc<<16|in  3.2 MB
constexpr size_t OFF_ENT2  = OFF_ENT + 3200000;      // u32 [E] rel<<16|in  3.2 MB
constexpr size_t OFF_BINW  = OFF_ENT2 + 3200000;     // f16 [E][8]         12.8 MB (bin-ordered)
static_assert(OFF_EFH % 16 == 0 && OFF_BINW % 16 == 0, "alignment");

typedef __attribute__((ext_vector_type(8))) short short8;
typedef __attribute__((ext_vector_type(4))) float f32x4;
typedef __attribute__((ext_vector_type(8))) _Float16 f16x8;

__device__ inline unsigned short f2bf(float x) {  // fp32 -> bf16, RNE
    unsigned int u = __float_as_uint(x);
    unsigned int r = (u + 0x7FFFu + ((u >> 16) & 1u)) >> 16;
    return (unsigned short)r;
}
__device__ inline float bf2f(unsigned short u) {
    return __uint_as_float(((unsigned int)u) << 16);
}

// ---------------------------------------------------------------------------
// Fused prep:
//   [0, 3125)            nf -> bf16
//   [3125, 3157)         K transpose -> K_T
//   [3157, 6282)         ef transpose+convert -> efh[e][8] fp16 (coalesced)
//   [6282, 6478)         per-chunk LDS bin-histogram -> counts[bin][chunk]
// No global atomics anywhere.
// ---------------------------------------------------------------------------
constexpr int NF_BLOCKS = N_IN * C / 4 / 256;  // 3125 (exact)
constexpr int KT_BLOCKS = 32;
constexpr int ET_BLOCKS = E / 256;             // 3125 (exact)
constexpr int BH_BLOCKS = NCHUNK;              // 196

__global__ __launch_bounds__(256) void prep_kernel(const float* __restrict__ nf,
                                                   const float* __restrict__ Kmat,
                                                   const float* __restrict__ ef,
                                                   const int* __restrict__ idx,
                                                   unsigned short* __restrict__ nf_bf,
                                                   unsigned short* __restrict__ K_T,
                                                   _Float16* __restrict__ efh,
                                                   int* __restrict__ counts) {
    __shared__ int hist[NBIN_S];
    const int b   = blockIdx.x;
    const int tid = threadIdx.x;

    if (b < NF_BLOCKS) {
        int i = b * 256 + tid;  // float4 units; 800000 exact
        float4 v = ((const float4*)nf)[i];
        unsigned int u0 = (unsigned int)f2bf(v.x) | ((unsigned int)f2bf(v.y) << 16);
        unsigned int u1 = (unsigned int)f2bf(v.z) | ((unsigned int)f2bf(v.w) << 16);
        ((uint2*)nf_bf)[i] = make_uint2(u0, u1);
    } else if (b < NF_BLOCKS + KT_BLOCKS) {
        for (int k = (b - NF_BLOCKS) * 256 + tid; k < T * C * F; k += KT_BLOCKS * 256) {
            int f = k & 63;
            int c = (k >> 6) & 63;
            int t = k >> 12;
            K_T[f * 512 + t * 64 + c] = f2bf(Kmat[k]);
        }
    } else if (b < NF_BLOCKS + KT_BLOCKS + ET_BLOCKS) {
        int e = (b - NF_BLOCKS - KT_BLOCKS) * 256 + tid;  // 800000 exact
        f16x8 h;
#pragma unroll
        for (int t = 0; t < T; ++t)
            h[t] = (_Float16)ef[(size_t)t * E + e];  // coalesced per t; RNE cvt
        *(f16x8*)(efh + (size_t)e * 8) = h;          // 16B coalesced store
    } else {
        const int c = b - NF_BLOCKS - KT_BLOCKS - ET_BLOCKS;  // chunk id
        for (int i = tid; i < NBIN_S; i += 256) hist[i] = 0;
        __syncthreads();
        const int e0 = c * CHUNK;
        const int n  = min(CHUNK, E - e0);
        for (int i = tid; i < n; i += 256) {
            int o = ((const int2*)idx)[e0 + i].x;
            atomicAdd(&hist[o >> 8], 1);  // LDS atomic
        }
        __syncthreads();
        for (int i = tid; i < NBIN_S; i += 256)
            counts[i * NCHUNK + c] = hist[i];  // bin-major for the scan
    }
}

// ---------------------------------------------------------------------------
// Scan pass A over counts[LEN_CNT]: per-256-chunk exclusive scan in place.
// ---------------------------------------------------------------------------
__global__ __launch_bounds__(256) void scanA_kernel(int* __restrict__ a,
                                                    int* __restrict__ bsum) {
    __shared__ int sh[256];
    const int tid = threadIdx.x;
    int g = blockIdx.x * 256 + tid;
    int v = (g < LEN_CNT) ? a[g] : 0;
    sh[tid] = v;
    __syncthreads();
#pragma unroll
    for (int off = 1; off < 256; off <<= 1) {
        int x = 0;
        if (tid >= off) x = sh[tid - off];
        __syncthreads();
        if (tid >= off) sh[tid] += x;
        __syncthreads();
    }
    int incl = sh[tid];
    if (g < LEN_CNT) a[g] = incl - v;
    if (tid == 255) bsum[blockIdx.x] = incl;
}

// ---------------------------------------------------------------------------
// Scan pass BC: each block adds sum(bsum[0..bi)).  SCA(151) < 256.
// ---------------------------------------------------------------------------
__global__ __launch_bounds__(256) void scanBC_kernel(int* __restrict__ a,
                                                     const int* __restrict__ bsum) {
    __shared__ int sh[256];
    const int bi  = blockIdx.x;
    const int tid = threadIdx.x;
    sh[tid] = (tid < bi) ? bsum[tid] : 0;
    __syncthreads();
#pragma unroll
    for (int off = 128; off >= 1; off >>= 1) {
        if (tid < off) sh[tid] += sh[tid + off];
        __syncthreads();
    }
    const int offset = sh[0];
    int g = bi * 256 + tid;
    if (g < LEN_CNT) a[g] += offset;
}

// ---------------------------------------------------------------------------
// binscatter: chunk c places its edges into per-(bin,chunk) runs.
// Entry is now 4 B (loc<<16 | in; in < 2^16 since N_IN=50000) and the
// edge's 8 fp16 weights ride along into binw[pos] (16 B): read COALESCED
// from efh (e chunk-contiguous), written run-local (L2-merged). The edge id
// disappears from the pipeline entirely.
// ---------------------------------------------------------------------------
__global__ __launch_bounds__(512) void binscatter_kernel(const int* __restrict__ idx,
                                                         const int* __restrict__ offs,
                                                         const _Float16* __restrict__ efh,
                                                         unsigned* __restrict__ ent,
                                                         _Float16* __restrict__ binw) {
    __shared__ int cur[NBIN_S];
    const int tid = threadIdx.x;
    const int c   = blockIdx.x;
    const f16x8* efh8 = (const f16x8*)efh;
    f16x8* binw8 = (f16x8*)binw;
    for (int i = tid; i < NBIN_S; i += 512) cur[i] = offs[i * NCHUNK + c];
    __syncthreads();
    const int e0 = c * CHUNK;
    const int n  = min(CHUNK, E - e0);
    for (int i = tid; i < n; i += 512) {
        int2 oi = ((const int2*)idx)[e0 + i];  // {out, in}, coalesced 8B
        int bin = oi.x >> 8;
        int loc = oi.x & 255;
        f16x8 w = efh8[e0 + i];                // coalesced 16B read
        int pos = atomicAdd(&cur[bin], 1);
        ent[pos]   = ((unsigned)loc << 16) | (unsigned)oi.y;
        binw8[pos] = w;                        // run-local 16B write
    }
}

// ---------------------------------------------------------------------------
// permfix: block = one bin (256 nodes). (1) LDS 256-hist + scan -> node
// starts (writes global start[]); (2) scatter entries to exact node-sorted
// slots as u32 {rel(13b)<<16 | in(16b)} where rel = i - W0 is the BIN-LOCAL
// weight index into binw (bin edge count ~4082 +- 64 << 8192). Writes
// confined to the bin's block-exclusive ~16KB window.
// ---------------------------------------------------------------------------
__global__ __launch_bounds__(512) void permfix_kernel(const int* __restrict__ offs,
                                                      const unsigned* __restrict__ ent,
                                                      int* __restrict__ start_g,
                                                      unsigned* __restrict__ ent2) {
    __shared__ int hist[256];
    __shared__ int sc[256];
    __shared__ int cur[256];
    const int tid = threadIdx.x;
    const int b   = blockIdx.x;
    const int W0  = offs[b * NCHUNK];
    const int W1  = (b + 1 < NBIN_S) ? offs[(b + 1) * NCHUNK] : E;

    if (tid < 256) hist[tid] = 0;
    __syncthreads();
    for (int i = W0 + tid; i < W1; i += 512)
        atomicAdd(&hist[ent[i] >> 16], 1);
    __syncthreads();

    // inclusive scan of hist[256] on threads 0-255 (512-thread-safe barriers)
    if (tid < 256) sc[tid] = hist[tid];
    __syncthreads();
    for (int off = 1; off < 256; off <<= 1) {
        int x = 0;
        if (tid < 256 && tid >= off) x = sc[tid - off];
        __syncthreads();
        if (tid < 256 && tid >= off) sc[tid] += x;
        __syncthreads();
    }
    if (tid < 256) {
        int s = W0 + sc[tid] - hist[tid];  // exclusive
        int g = b * 256 + tid;
        if (g < N_OUT) start_g[g] = s;
        cur[tid] = s;
    }
    if (b == NBIN_S - 1 && tid == 0) start_g[N_OUT] = E;
    __syncthreads();

    for (int i = W0 + tid; i < W1; i += 512) {
        unsigned u = ent[i];
        int loc = (int)(u >> 16);
        int pos = atomicAdd(&cur[loc], 1);
        ent2[pos] = ((unsigned)(i - W0) << 16) | (u & 0xFFFFu);  // rel | in
    }
}

// ---------------------------------------------------------------------------
// Aggregate: block = 4 waves = 16 output nodes, XCD-swizzled.
//  Bijective swizzle (m204) maps the 16 blocks of each 256-node bin onto the
//  SAME XCD, so the bin's ~65KB binw weight window is fetched ~once into
//  that XCD's L2 and then hit by all 16 blocks (round-7 paid ~35MB of
//  table-global random weight misses; now ~13MB streamed-once).
//  Phase 1 (per wave, 4 nodes, lane=c):
//    preload 64 packed {rel,in} u32 entries coalesced, readlane-broadcast;
//    4-edge unroll -> 4 independent 128 B nf gathers in flight; weights via
//    wave-uniform 16B loads from binw[Wbase+rel] (bin-window-local).
//  Phase 2 (per wave, one 16-col f-tile):
//    out_tile(16x64) = A(16x512) @ K_T^T via 16 chained mfma_f32_16x16x32_bf16
// ---------------------------------------------------------------------------
__global__ __launch_bounds__(256) void aggregate_kernel(const unsigned short* __restrict__ nf_bf,
                                                        const unsigned short* __restrict__ K_T,
                                                        const int* __restrict__ start,
                                                        const unsigned* __restrict__ ent2,
                                                        const _Float16* __restrict__ binw,
                                                        const int* __restrict__ offs,
                                                        const float* __restrict__ bias,
                                                        float* __restrict__ out) {
    __shared__ unsigned short A_lds[16][520];  // +8 pad

    // bijective XCD swizzle: 3125 blocks over 8 XCDs (q=390, r=5)
    constexpr int NWG = N_OUT / 16;  // 3125
    constexpr int Q = NWG / 8, R = NWG % 8;
    const int xc = blockIdx.x & 7;
    const int sl = blockIdx.x >> 3;
    const int orig = (xc < R ? xc * (Q + 1) : R * (Q + 1) + (xc - R) * Q) + sl;

    const int wave = threadIdx.x >> 6;
    const int lane = threadIdx.x & 63;
    const int node_base = orig * 16;
    const int Wbase = offs[(orig >> 4) * NCHUNK];  // bin's binw window base

    const f16x8* binw8 = (const f16x8*)binw;

    // ---- Phase 1: segment aggregation ----
    for (int q = 0; q < 4; ++q) {
        const int m = wave * 4 + q;
        const int o = node_base + m;
        const int s0 = __builtin_amdgcn_readfirstlane(start[o]);
        const int s1 = __builtin_amdgcn_readfirstlane(start[o + 1]);

        float acc[8] = {0.f, 0.f, 0.f, 0.f, 0.f, 0.f, 0.f, 0.f};

        for (int base = s0; base < s1; base += 64) {
            const int cnt = min(64, s1 - base);
            // coalesced preload of this chunk's packed {rel, in} entries
            int vv = (base + lane < s1) ? (int)ent2[base + lane] : 0;

            int j = 0;
            for (; j + 4 <= cnt; j += 4) {
                const int v0 = __builtin_amdgcn_readlane(vv, j + 0);
                const int v1 = __builtin_amdgcn_readlane(vv, j + 1);
                const int v2 = __builtin_amdgcn_readlane(vv, j + 2);
                const int v3 = __builtin_amdgcn_readlane(vv, j + 3);
                // 4 independent 128 B gathers in flight
                float x0 = bf2f(nf_bf[(size_t)(v0 & 0xFFFF) * 64 + lane]);
                float x1 = bf2f(nf_bf[(size_t)(v1 & 0xFFFF) * 64 + lane]);
                float x2 = bf2f(nf_bf[(size_t)(v2 & 0xFFFF) * 64 + lane]);
                float x3 = bf2f(nf_bf[(size_t)(v3 & 0xFFFF) * 64 + lane]);
                // wave-uniform weight loads from the bin-local window
                f16x8 w0 = binw8[(size_t)(Wbase + (v0 >> 16))];
                f16x8 w1 = binw8[(size_t)(Wbase + (v1 >> 16))];
                f16x8 w2 = binw8[(size_t)(Wbase + (v2 >> 16))];
                f16x8 w3 = binw8[(size_t)(Wbase + (v3 >> 16))];
#pragma unroll
                for (int t = 0; t < T; ++t) {
                    acc[t] += (float)w0[t] * x0;
                    acc[t] += (float)w1[t] * x1;
                    acc[t] += (float)w2[t] * x2;
                    acc[t] += (float)w3[t] * x3;
                }
            }
            for (; j < cnt; ++j) {
                const int v0 = __builtin_amdgcn_readlane(vv, j);
                float x0 = bf2f(nf_bf[(size_t)(v0 & 0xFFFF) * 64 + lane]);
                f16x8 w0 = binw8[(size_t)(Wbase + (v0 >> 16))];
#pragma unroll
                for (int t = 0; t < T; ++t) acc[t] += (float)w0[t] * x0;
            }
        }

#pragma unroll
        for (int t = 0; t < T; ++t) A_lds[m][t * 64 + lane] = f2bf(acc[t]);
    }
    __syncthreads();

    // ---- Phase 2: MFMA epilogue; wave handles f-tile [wave*16, wave*16+16) ----
    const int mrow = lane & 15;
    const int kb   = lane >> 4;
    const int fcol = wave * 16 + mrow;

    f32x4 acc4 = {0.f, 0.f, 0.f, 0.f};
#pragma unroll
    for (int s = 0; s < 16; ++s) {
        const int k0 = s * 32 + kb * 8;
        short8 a = *(const short8*)&A_lds[mrow][k0];
        short8 b = *(const short8*)(K_T + (size_t)fcol * 512 + k0);
        acc4 = __builtin_amdgcn_mfma_f32_16x16x32_bf16(a, b, acc4, 0, 0, 0);
    }

    const float bv = bias[fcol];
#pragma unroll
    for (int r = 0; r < 4; ++r) {
        const int m = kb * 4 + r;
        out[(size_t)(node_base + m) * F + fcol] = acc4[r] + bv;
    }
}

// ---------------------------------------------------------------------------
extern "C" void kernel_launch(void* const* d_in, const int* in_sizes, int n_in,
                              void* d_out, int out_size, void* d_ws, size_t ws_size,
                              hipStream_t stream) {
    const float* nf   = (const float*)d_in[0];  // (N_IN, C)
    const float* ef   = (const float*)d_in[1];  // (T, E)
    const int*   idx  = (const int*)d_in[2];    // (E, 2) int32 on device
    const float* Kmat = (const float*)d_in[3];  // (T, C, F)
    const float* bias = (const float*)d_in[4];  // (F,)
    float*       out  = (float*)d_out;          // (N_OUT, F)

    char* ws = (char*)d_ws;
    unsigned short* nf_bf  = (unsigned short*)(ws + OFF_NFBF);
    unsigned short* K_T    = (unsigned short*)(ws + OFF_KT);
    int*            counts = (int*)(ws + OFF_CNT);    // becomes offs[]
    int*            bsum   = (int*)(ws + OFF_BSUM);
    int*            start  = (int*)(ws + OFF_START);
    _Float16*       efh    = (_Float16*)(ws + OFF_EFH);
    unsigned*       ent    = (unsigned*)(ws + OFF_ENT);
    unsigned*       ent2   = (unsigned*)(ws + OFF_ENT2);
    _Float16*       binw   = (_Float16*)(ws + OFF_BINW);

    // no memset needed: counts/start/ent are fully written by the pipeline
    prep_kernel<<<NF_BLOCKS + KT_BLOCKS + ET_BLOCKS + BH_BLOCKS, 256, 0, stream>>>(
        nf, Kmat, ef, idx, nf_bf, K_T, efh, counts);
    scanA_kernel<<<SCA, 256, 0, stream>>>(counts, bsum);
    scanBC_kernel<<<SCA, 256, 0, stream>>>(counts, bsum);
    binscatter_kernel<<<NCHUNK, 512, 0, stream>>>(idx, counts, efh, ent, binw);
    permfix_kernel<<<NBIN_S, 512, 0, stream>>>(counts, ent, start, ent2);
    aggregate_kernel<<<N_OUT / 16, 256, 0, stream>>>(
        nf_bf, K_T, start, ent2, binw, counts, bias, out);
}